// Round 1
// baseline (324.613 us; speedup 1.0000x reference)
//
#include <hip/hip_runtime.h>
#include <hip/hip_bf16.h>

// Problem constants
#define B_ 16
#define L_ 1024
#define H_ 1024
#define N_ 64
// M = B*L = 16384, K = H = 1024, output cols = 2H = 2048 (a|g pairs)
// Chunked SSM: T=64 chunk, 16 chunks/seq.

typedef __bf16 bf16x8 __attribute__((ext_vector_type(8)));
typedef float  f32x4  __attribute__((ext_vector_type(4)));
typedef unsigned short u16x8 __attribute__((ext_vector_type(8)));

// async global->LDS, 16B per lane; LDS dest is wave-uniform base + lane*16
__device__ __forceinline__ void gll16(const void* g, void* l) {
    __builtin_amdgcn_global_load_lds(
        (const __attribute__((address_space(1))) unsigned int*)g,
        (__attribute__((address_space(3))) unsigned int*)l,
        16, 0, 0);
}

__device__ __forceinline__ float gelu_tanh(float yv) {
    float u = yv + 0.044715f * yv * yv * yv;
    return 0.5f * yv * (1.0f + tanhf(0.7978845608028654f * u));
}

// ---------------------------------------------------------------------------
// K0 "prep": one kernel, 2176 blocks x 256 threads.
//  [0,1024):    x [B,L,H] f32 -> xTb [B*H, L] bf16   (LDS-free transpose:
//               scattered 16B float4 reads (L1-resident), coalesced 128B
//               row writes)
//  [1024,1152): W [1024,2048] f32 -> Wt [2048,1024] bf16 (same scheme)
//  [1152,2176): build_tables (Bt/Qt/wT), one h per block
//  LDS shrunk 36608B -> 2304B (w-power tables recomputed on the fly,
//  bitwise-identical formulas) so occupancy is 8 blocks/CU instead of 4:
//  the transpose blocks are latency-bound on scattered 16B reads and need
//  the extra waves in flight.
// ---------------------------------------------------------------------------
__global__ __launch_bounds__(256) void prep(
        const float* __restrict__ x, const float* __restrict__ log_dt,
        const float* __restrict__ Arl, const float* __restrict__ Aim,
        const float* __restrict__ Cr, const float* __restrict__ Ci,
        const float* __restrict__ W,
        __hip_bfloat16* __restrict__ xTb, __hip_bfloat16* __restrict__ Bt,
        __hip_bfloat16* __restrict__ Qt, float2* __restrict__ wT,
        __hip_bfloat16* __restrict__ Wt) {
    __shared__ char sm[2304];
    int idx = blockIdx.x, t = threadIdx.x;
    int wv = t >> 6, lane = t & 63;

    if (idx < 1024) {
        // ---- x transpose: block covers b, l-tile 64, h-range 256 ----
        int b = idx >> 6, lt = (idx >> 2) & 15, ht = idx & 3;
        int l0 = lt * 64;
        int hb0 = ht * 256 + wv * 64;
        const float* src = x + ((size_t)b * L_ + l0 + lane) * H_;
#pragma unroll
        for (int j = 0; j < 16; ++j) {
            float4 v = *(const float4*)(src + hb0 + j * 4);
            int hh = hb0 + j * 4;
            __hip_bfloat16* dp = xTb + ((size_t)b * H_ + hh) * L_ + l0 + lane;
            dp[0]        = __float2bfloat16(v.x);
            dp[L_]       = __float2bfloat16(v.y);
            dp[2 * L_]   = __float2bfloat16(v.z);
            dp[3 * L_]   = __float2bfloat16(v.w);
        }
        return;
    }
    if (idx < 1152) {
        // ---- W transpose: block covers k-tile 64 (lanes), n-range 256 ----
        int id2 = idx - 1024;
        int kt = id2 >> 3, ntile = id2 & 7;
        int k0 = kt * 64;
        int nb0 = ntile * 256 + wv * 64;
        const float* src = W + ((size_t)(k0 + lane)) * 2048;
#pragma unroll
        for (int j = 0; j < 16; ++j) {
            float4 v = *(const float4*)(src + nb0 + j * 4);
            int nn = nb0 + j * 4;
            __hip_bfloat16* dp = Wt + (size_t)nn * H_ + k0 + lane;
            dp[0]      = __float2bfloat16(v.x);
            dp[H_]     = __float2bfloat16(v.y);
            dp[2 * H_] = __float2bfloat16(v.z);
            dp[3 * H_] = __float2bfloat16(v.w);
        }
        return;
    }
    // ---- build_tables: h = idx - 1152 ----
    // w^j powers recomputed per consumer (3x transcendentals, ~free at this
    // occupancy) instead of cached in 34KB of LDS.
    {
        float* drs  = (float*)sm;            // [64]
        float* dis  = (float*)(sm + 256);    // [64]
        float* c2rs = (float*)(sm + 512);    // [64]
        float* c2is = (float*)(sm + 768);    // [64]
        float (*kp)[64] = (float(*)[64])(sm + 1024);  // [4][64]
        float* kv   = (float*)(sm + 2048);   // [64]
        int h = idx - 1152;

        if (t < 64) {
            int n = t, i = h * 64 + n;
            float dt = expf(log_dt[h]);
            float ar = -expf(Arl[i]), ai = Aim[i];
            float dr = dt * ar, di = dt * ai;
            drs[n] = dr; dis[n] = di;
            float e = expf(dr);
            float wr = e * cosf(di), wi = e * sinf(di);
            float em1r = wr - 1.0f, em1i = wi;
            float Crv = Cr[i], Civ = Ci[i];
            float tr = Crv * em1r - Civ * em1i;
            float ti = Crv * em1i + Civ * em1r;
            float inv = 1.0f / (ar * ar + ai * ai);
            c2rs[n] = 2.0f * (tr * ar + ti * ai) * inv;
            c2is[n] = 2.0f * (ti * ar - tr * ai) * inv;
            // w^64 for the chunk-scan carry
            float jf = 64.0f;
            float er64 = expf(jf * dr);
            float ph64 = jf * di;
            wT[h * 64 + n] = make_float2(er64 * cosf(ph64), er64 * sinf(ph64));
        }
        __syncthreads();
        // kv[j] = sum_n c2r*Re(w^j) - c2i*Im(w^j), partial sums per 16-n part
        {
            int j = t & 63, part = t >> 6;
            float jf = (float)j;
            float s = 0.0f;
            for (int nn = part * 16; nn < part * 16 + 16; ++nn) {
                float er = expf(jf * drs[nn]);
                float ph = jf * dis[nn];
                float wr = er * cosf(ph), wi = er * sinf(ph);
                s += c2rs[nn] * wr - c2is[nn] * wi;
            }
            kp[part][j] = s;
        }
        __syncthreads();
        if (t < 64) kv[t] = kp[0][t] + kp[1][t] + kp[2][t] + kp[3][t];
        __syncthreads();
        // Bt rows 0..63: causal lower-triangular kernel
#pragma unroll
        for (int it = 0; it < 16; ++it) {
            int id3 = it * 256 + t, row = id3 >> 6, col = id3 & 63;
            int d = row - col;
            float v = (d >= 0) ? kv[d] : 0.0f;
            Bt[(size_t)(h * 192 + row) * 64 + col] = __float2bfloat16(v);
        }
        // Bt rows 64..191: w^(63-j) powers, rows 64+2n (Re) / 64+2n+1 (Im)
#pragma unroll
        for (int it = 0; it < 16; ++it) {
            int id3 = it * 256 + t;
            int n = id3 >> 6, j = id3 & 63;
            float jf = (float)(63 - j);
            float er = expf(jf * drs[n]);
            float ph = jf * dis[n];
            float wr = er * cosf(ph), wi = er * sinf(ph);
            Bt[(size_t)(h * 192 + 64 + 2 * n) * 64 + j]     = __float2bfloat16(wr);
            Bt[(size_t)(h * 192 + 64 + 2 * n + 1) * 64 + j] = __float2bfloat16(wi);
        }
        // Qt: row trow, col pair (2n, 2n+1) = (Re, -Im) of c2 * w^(trow+1)
#pragma unroll
        for (int it = 0; it < 16; ++it) {
            int id3 = it * 256 + t;
            int trow = id3 >> 6, n = id3 & 63;
            float jf = (float)(trow + 1);
            float er = expf(jf * drs[n]);
            float ph = jf * dis[n];
            float wr = er * cosf(ph), wi = er * sinf(ph);
            float cR = c2rs[n] * wr - c2is[n] * wi;
            float cI = c2rs[n] * wi + c2is[n] * wr;
            __hip_bfloat16* qp = Qt + (size_t)(h * 64 + trow) * 128 + 2 * n;
            qp[0] = __float2bfloat16(cR);
            qp[1] = __float2bfloat16(-cI);
        }
    }
}

// ---------------------------------------------------------------------------
// K2: fused chunked SSM (M=64 rows = 4 batches, 48K LDS, 3 blocks/CU).
// sX now staged via gll16 from bf16 xTb; epilogue D-skip reads bf16 x.
// XCD swizzle: the 4 blocks sharing h get blockIdx ≡ same (mod 8).
// LDS: phase1 sX[64][128B]@0 8K, sB[192][128B]@8K 24K, sQ[64][256B]@32K 16K;
//      phase2 sS f32[64 rows][512B]@0 32K (overlays sX+sB; sQ disjoint).
// ---------------------------------------------------------------------------
__global__ __launch_bounds__(256, 3) void chunk_scan(
        const __hip_bfloat16* __restrict__ xTb, const char* __restrict__ Btg,
        const char* __restrict__ Qtg, const float2* __restrict__ wTg,
        const float* __restrict__ Dv, __hip_bfloat16* __restrict__ yTa) {
    __shared__ char lds[49152];
    char* sX = lds;              // [64][128B]
    char* sB = lds + 8192;       // [192][128B]
    char* sS = lds;              // [64 rows][512B] f32, post-GEMM1 overlay
    char* sQ = lds + 32768;      // [64][256B]

    int tid = threadIdx.x, wv = tid >> 6, lane = tid & 63;
    int lm = lane & 15, q = lane >> 4, r8 = lane >> 3, c8 = lane & 7;
    // XCD-aware decode: h = (idx>>5)*8 + (idx&7); member m = (idx>>3)&3
    int idx = blockIdx.x;
    int h  = ((idx >> 5) << 3) | (idx & 7);
    int b0 = ((idx >> 3) & 3) * 4;

    int csrc = c8 ^ r8;
    // ---- stage sB: 24 wave-loads of 8 rows x 128B ----
#pragma unroll
    for (int j = 0; j < 6; ++j) {
        int i = wv * 6 + j;
        gll16(Btg + ((size_t)(h * 192 + i * 8 + r8)) * 128 + csrc * 16,
              sB + i * 1024);
    }
    // ---- stage sQ: 16 wave-loads of 4 rows x 256B ----
    {
        int r4 = lane >> 4, c16 = lane & 15;
#pragma unroll
        for (int j = 0; j < 4; ++j) {
            int i = wv * 4 + j;
            gll16(Qtg + (size_t)(h * 64 + i * 4 + r4) * 256 + (c16 ^ r4) * 16,
                  sQ + i * 1024);
        }
    }
    // ---- stage sX via gll16: 8 groups of 8 rows x 128B, 2 per wave ----
    {
        const char* xb = (const char*)xTb;
#pragma unroll
        for (int j = 0; j < 2; ++j) {
            int i = wv * 2 + j;                      // row group
            int bp = b0 + (i >> 1);                  // batch of this group
            int ch = (i & 1) * 8 + r8;               // chunk index (row&15)
            gll16(xb + ((size_t)(bp * H_ + h)) * 2048 + ch * 128 + csrc * 16,
                  sX + i * 1024);
        }
    }
    __syncthreads();

    // ---- GEMM1: wave rows wv*16+lm, N=192 (12 tiles), K=64 ----
    f32x4 acc[12];
#pragma unroll
    for (int nt = 0; nt < 12; ++nt) acc[nt] = (f32x4){0.f, 0.f, 0.f, 0.f};
#pragma unroll
    for (int kk = 0; kk < 2; ++kk) {
        int clog = kk * 4 + q;
        int m = wv * 16 + lm;
        bf16x8 af = *(const bf16x8*)(sX + m * 128 + ((clog ^ (m & 7)) * 16));
#pragma unroll
        for (int nt = 0; nt < 12; ++nt) {
            int nrow = nt * 16 + lm;
            bf16x8 bf = *(const bf16x8*)(sB + nrow * 128 + ((clog ^ (nrow & 7)) * 16));
            acc[nt] = __builtin_amdgcn_mfma_f32_16x16x32_bf16(
                af, bf, acc[nt], 0, 0, 0);
        }
    }
    __syncthreads();   // everyone done with sX/sB -> sS overlay is safe

    // ---- write Sloc (nt 4..11 -> ri 0..127) into sS f32 swizzled ----
#pragma unroll
    for (int nt = 4; nt < 12; ++nt) {
        int ri = (nt - 4) * 16 + lm;
#pragma unroll
        for (int r = 0; r < 4; ++r) {
            int row = wv * 16 + q * 4 + r;
            *(float*)(sS + row * 512 + (((ri >> 2) ^ (row & 7)) * 16)
                      + (ri & 3) * 4) = acc[nt][r];
        }
    }
    __syncthreads();

    // ---- serial chunk scan: one chain per thread (n = tid&63, bp = wv) ----
    {
        int n = tid & 63, bp = tid >> 6;
        float2 wt = wTg[h * 64 + n];             // w^64
        float sr = 0.0f, si = 0.0f;
#pragma unroll 1
        for (int c = 0; c < 16; ++c) {
            int row = bp * 16 + c;
            char* p = sS + row * 512 + (((n >> 1) ^ (row & 7)) * 16)
                      + (n & 1) * 8;
            float2 loc = *(float2*)p;
            *(float2*)p = make_float2(sr, si);   // S_in before update
            float nr2 = wt.x * sr - wt.y * si + loc.x;
            float ni2 = wt.x * si + wt.y * sr + loc.y;
            sr = nr2; si = ni2;
        }
    }
    __syncthreads();

    // ---- GEMM2: y += S_in[64 x 128] * Qt^T, K=128 (4 k-steps) ----
#pragma unroll
    for (int ks = 0; ks < 4; ++ks) {
        int row = wv * 16 + lm;
        int cf0 = ks * 8 + q * 2;
        f32x4 a0 = *(const f32x4*)(sS + row * 512 + ((cf0 ^ (row & 7)) * 16));
        f32x4 a1 = *(const f32x4*)(sS + row * 512 + (((cf0 + 1) ^ (row & 7)) * 16));
        bf16x8 af;
        af[0] = (__bf16)a0[0]; af[1] = (__bf16)a0[1];
        af[2] = (__bf16)a0[2]; af[3] = (__bf16)a0[3];
        af[4] = (__bf16)a1[0]; af[5] = (__bf16)a1[1];
        af[6] = (__bf16)a1[2]; af[7] = (__bf16)a1[3];
#pragma unroll
        for (int nt = 0; nt < 4; ++nt) {
            int trow = nt * 16 + lm;
            int clog = ks * 4 + q;
            bf16x8 bq = *(const bf16x8*)(sQ + trow * 256 + ((clog ^ (trow & 3)) * 16));
            acc[nt] = __builtin_amdgcn_mfma_f32_16x16x32_bf16(
                af, bq, acc[nt], 0, 0, 0);
        }
    }

    // ---- epilogue: D-skip (bf16 x) + GELU -> yTa ----
    float Dh = Dv[h];
#pragma unroll
    for (int nt = 0; nt < 4; ++nt)
#pragma unroll
        for (int r = 0; r < 4; ++r) {
            int row = wv * 16 + q * 4 + r;
            int seq = (b0 + (row >> 4)) * H_ + h;
            int l   = (row & 15) * 64 + nt * 16 + lm;
            float xv = __bfloat162float(xTb[(size_t)seq * L_ + l]);
            float yv = acc[nt][r] + xv * Dh;
            yTa[(size_t)seq * L_ + l] = __float2bfloat16(gelu_tanh(yv));
        }
}

// ---------------------------------------------------------------------------
// K3: yTa [B*H, L] bf16 -> Y [B*L, H] bf16  (LDS-free: scattered 16B reads
// (L1-resident), coalesced 128B stores). 1024 blocks x 256 thr.
// ---------------------------------------------------------------------------
__global__ __launch_bounds__(256) void transpose_y(
        const unsigned short* __restrict__ yT, unsigned short* __restrict__ Y) {
    int idx = blockIdx.x, t = threadIdx.x;
    int wv = t >> 6, lane = t & 63;
    int b = idx >> 6, lt = (idx >> 2) & 15, ht = idx & 3;
    int l0 = lt * 64;
    int hl = ht * 256 + wv * 64 + lane;
    const unsigned short* src = yT + ((size_t)b * H_ + hl) * L_ + l0;
#pragma unroll
    for (int kk = 0; kk < 8; ++kk) {
        u16x8 v = *(const u16x8*)(src + kk * 8);
#pragma unroll
        for (int e = 0; e < 8; ++e)
            Y[((size_t)b * L_ + l0 + kk * 8 + e) * H_ + hl] = v[e];
    }
}

// ---------------------------------------------------------------------------
// K4: Z = Y @ Wt^T (+b), fused GLU epilogue (unchanged)
// ---------------------------------------------------------------------------
__global__ __launch_bounds__(256, 2) void gemm_glu(
        const __hip_bfloat16* __restrict__ Y, const __hip_bfloat16* __restrict__ Wt,
        const float* __restrict__ bv, float* __restrict__ out) {
    __shared__ char lds[32768];
    char* sA  = lds;             // [128 rows][8 chunks * 16B] = 16 KiB
    char* sBa = lds + 16384;     // [64][128B] = 8 KiB
    char* sBg = lds + 24576;     // [64][128B] = 8 KiB

    int tid = threadIdx.x, wv = tid >> 6, lane = tid & 63;
    int mb = (blockIdx.x & 127) * 128;
    int h0 = (blockIdx.x >> 7) * 64;
    int r8 = lane >> 3, c8 = lane & 7, csrc = c8 ^ r8;
    int wm = (wv >> 1) * 64, wn = (wv & 1) * 32;
    int lm = lane & 15, q = lane >> 4;

    const char* Yb = (const char*)Y;
    const char* Wb = (const char*)Wt;

    f32x4 accA[4][2], accG[4][2];
#pragma unroll
    for (int i = 0; i < 4; ++i)
#pragma unroll
        for (int j = 0; j < 2; ++j) {
            accA[i][j] = (f32x4){0.f, 0.f, 0.f, 0.f};
            accG[i][j] = (f32x4){0.f, 0.f, 0.f, 0.f};
        }

    for (int kt = 0; kt < 16; ++kt) {
        int k0b = kt * 128;
        __syncthreads();
#pragma unroll
        for (int j = 0; j < 4; ++j) {
            int i = wv * 4 + j;
            gll16(Yb + (size_t)(mb + i * 8 + r8) * 2048 + k0b + csrc * 16,
                  sA + i * 1024);
        }
#pragma unroll
        for (int j = 0; j < 2; ++j) {
            int i = wv * 2 + j;
            int n = h0 + i * 8 + r8;
            gll16(Wb + (size_t)n * 2048 + k0b + csrc * 16, sBa + i * 1024);
            gll16(Wb + (size_t)(n + 1024) * 2048 + k0b + csrc * 16, sBg + i * 1024);
        }
        __syncthreads();
#pragma unroll
        for (int kk = 0; kk < 2; ++kk) {
            int clog = kk * 4 + q;
            bf16x8 af[4], ba[2], bg[2];
#pragma unroll
            for (int mt = 0; mt < 4; ++mt) {
                int m = wm + mt * 16 + lm;
                af[mt] = *(const bf16x8*)(sA + m * 128 + ((clog ^ (m & 7)) * 16));
            }
#pragma unroll
            for (int nt = 0; nt < 2; ++nt) {
                int n = wn + nt * 16 + lm;
                int cph = (clog ^ (n & 7)) * 16;
                ba[nt] = *(const bf16x8*)(sBa + n * 128 + cph);
                bg[nt] = *(const bf16x8*)(sBg + n * 128 + cph);
            }
#pragma unroll
            for (int mt = 0; mt < 4; ++mt)
#pragma unroll
                for (int nt = 0; nt < 2; ++nt) {
                    accA[mt][nt] = __builtin_amdgcn_mfma_f32_16x16x32_bf16(
                        af[mt], ba[nt], accA[mt][nt], 0, 0, 0);
                    accG[mt][nt] = __builtin_amdgcn_mfma_f32_16x16x32_bf16(
                        af[mt], bg[nt], accG[mt][nt], 0, 0, 0);
                }
        }
    }
#pragma unroll
    for (int mt = 0; mt < 4; ++mt)
#pragma unroll
        for (int nt = 0; nt < 2; ++nt) {
            int hc = h0 + wn + nt * 16 + lm;
            float bba = bv[hc], bbg = bv[hc + 1024];
#pragma unroll
            for (int r = 0; r < 4; ++r) {
                int m = mb + wm + mt * 16 + q * 4 + r;
                float za = accA[mt][nt][r] + bba;
                float zg = accG[mt][nt][r] + bbg;
                out[(size_t)m * H_ + hc] = za / (1.0f + expf(-zg));
            }
        }
}

// ---------------------------------------------------------------------------
extern "C" void kernel_launch(void* const* d_in, const int* in_sizes, int n_in,
                              void* d_out, int out_size, void* d_ws, size_t ws_size,
                              hipStream_t stream) {
    const float* x      = (const float*)d_in[0];
    const float* log_dt = (const float*)d_in[1];
    const float* Arl    = (const float*)d_in[2];
    const float* Aim    = (const float*)d_in[3];
    const float* Cr     = (const float*)d_in[4];
    const float* Ci     = (const float*)d_in[5];
    const float* Dv     = (const float*)d_in[6];
    const float* W      = (const float*)d_in[7];
    const float* bv     = (const float*)d_in[8];
    float* out = (float*)d_out;

    char* ws = (char*)d_ws;
    // layout:
    //   [0,  32M) xTb bf16          (reused as Ybf bf16 after chunk_scan)
    //   [32M,64M) yTa bf16
    //   [64M,88M) Bt | [88M,104M) Qt | [104M,104.5M) wT | [105M,109M) Wt
    __hip_bfloat16*  xTb = (__hip_bfloat16*)ws;
    __hip_bfloat16*  yTa = (__hip_bfloat16*)(ws + (32u << 20));
    __hip_bfloat16*  Ybf = (__hip_bfloat16*)ws;
    char*            Btg = ws + (64u << 20);
    char*            Qtg = Btg + (size_t)H_ * 192 * 64 * 2;          // +24M
    float2*          wTg = (float2*)(ws + (104u << 20));
    __hip_bfloat16*  Wt  = (__hip_bfloat16*)(ws + (105u << 20));

    prep<<<2176, 256, 0, stream>>>(x, log_dt, Arl, Aim, Cr, Ci, W,
                                   xTb, (__hip_bfloat16*)Btg,
                                   (__hip_bfloat16*)Qtg, wTg, Wt);
    chunk_scan<<<4096, 256, 0, stream>>>(xTb, Btg, Qtg, wTg, Dv, yTa);
    transpose_y<<<1024, 256, 0, stream>>>(
        (const unsigned short*)yTa, (unsigned short*)Ybf);
    gemm_glu<<<2048, 256, 0, stream>>>(Ybf, Wt, bv, out);
}

// Round 4
// 308.149 us; speedup vs baseline: 1.0534x; 1.0534x over previous
//
#include <hip/hip_runtime.h>
#include <hip/hip_bf16.h>

// Problem constants
#define B_ 16
#define L_ 1024
#define H_ 1024
#define N_ 64
// M = B*L = 16384, K = H = 1024, output cols = 2H = 2048 (a|g pairs)
// Chunked SSM: T=64 chunk, 16 chunks/seq.

typedef __bf16 bf16x8 __attribute__((ext_vector_type(8)));
typedef float  f32x4  __attribute__((ext_vector_type(4)));

// async global->LDS, 16B per lane; LDS dest is wave-uniform base + lane*16
__device__ __forceinline__ void gll16(const void* g, void* l) {
    __builtin_amdgcn_global_load_lds(
        (const __attribute__((address_space(1))) unsigned int*)g,
        (__attribute__((address_space(3))) unsigned int*)l,
        16, 0, 0);
}

// hardware transpose-read. Semantics (reconciles m156/m162 probes):
// lane supplies the address of ITS 64-bit slot; HW forms the 128B-aligned
// window W = addr & ~127, slot i = (addr>>3)&15, and delivers the 4 bf16 at
// bytes W + i*2 + j*32 (j=0..3) — i.e. column i of the window viewed as a
// [4][16] row-major bf16 subtile. Correct usage: addr = subtile_base + lm*8.
__device__ __forceinline__ unsigned long long tr16(unsigned a) {
    unsigned long long d;
    asm volatile("ds_read_b64_tr_b16 %0, %1" : "=v"(d) : "v"(a));
    return d;
}

__device__ __forceinline__ float gelu_tanh(float yv) {
    float u = yv + 0.044715f * yv * yv * yv;
    return 0.5f * yv * (1.0f + tanhf(0.7978845608028654f * u));
}

// ---------------------------------------------------------------------------
// K0 "prep": one kernel, 2176 blocks x 256 threads.
//  [0,1024):    x [B,L,H] f32 -> xTb [B*H, L] bf16   (LDS-free transpose:
//               scattered 16B float4 reads, coalesced 128B row writes)
//  [1024,1152): W [1024,2048] f32 -> Wt [2048,1024] bf16 (same scheme)
//  [1152,2176): build_tables (Bt/Qt/wT), one h per block
//  LDS 2304B (w-powers recomputed on the fly) -> 8 blocks/CU occupancy.
// ---------------------------------------------------------------------------
__global__ __launch_bounds__(256) void prep(
        const float* __restrict__ x, const float* __restrict__ log_dt,
        const float* __restrict__ Arl, const float* __restrict__ Aim,
        const float* __restrict__ Cr, const float* __restrict__ Ci,
        const float* __restrict__ W,
        __hip_bfloat16* __restrict__ xTb, __hip_bfloat16* __restrict__ Bt,
        __hip_bfloat16* __restrict__ Qt, float2* __restrict__ wT,
        __hip_bfloat16* __restrict__ Wt) {
    __shared__ char sm[2304];
    int idx = blockIdx.x, t = threadIdx.x;
    int wv = t >> 6, lane = t & 63;

    if (idx < 1024) {
        // ---- x transpose: block covers b, l-tile 64, h-range 256 ----
        int b = idx >> 6, lt = (idx >> 2) & 15, ht = idx & 3;
        int l0 = lt * 64;
        int hb0 = ht * 256 + wv * 64;
        const float* src = x + ((size_t)b * L_ + l0 + lane) * H_;
#pragma unroll
        for (int j = 0; j < 16; ++j) {
            float4 v = *(const float4*)(src + hb0 + j * 4);
            int hh = hb0 + j * 4;
            __hip_bfloat16* dp = xTb + ((size_t)b * H_ + hh) * L_ + l0 + lane;
            dp[0]        = __float2bfloat16(v.x);
            dp[L_]       = __float2bfloat16(v.y);
            dp[2 * L_]   = __float2bfloat16(v.z);
            dp[3 * L_]   = __float2bfloat16(v.w);
        }
        return;
    }
    if (idx < 1152) {
        // ---- W transpose: block covers k-tile 64 (lanes), n-range 256 ----
        int id2 = idx - 1024;
        int kt = id2 >> 3, ntile = id2 & 7;
        int k0 = kt * 64;
        int nb0 = ntile * 256 + wv * 64;
        const float* src = W + ((size_t)(k0 + lane)) * 2048;
#pragma unroll
        for (int j = 0; j < 16; ++j) {
            float4 v = *(const float4*)(src + nb0 + j * 4);
            int nn = nb0 + j * 4;
            __hip_bfloat16* dp = Wt + (size_t)nn * H_ + k0 + lane;
            dp[0]      = __float2bfloat16(v.x);
            dp[H_]     = __float2bfloat16(v.y);
            dp[2 * H_] = __float2bfloat16(v.z);
            dp[3 * H_] = __float2bfloat16(v.w);
        }
        return;
    }
    // ---- build_tables: h = idx - 1152 ----
    {
        float* drs  = (float*)sm;            // [64]
        float* dis  = (float*)(sm + 256);    // [64]
        float* c2rs = (float*)(sm + 512);    // [64]
        float* c2is = (float*)(sm + 768);    // [64]
        float (*kp)[64] = (float(*)[64])(sm + 1024);  // [4][64]
        float* kv   = (float*)(sm + 2048);   // [64]
        int h = idx - 1152;

        if (t < 64) {
            int n = t, i = h * 64 + n;
            float dt = expf(log_dt[h]);
            float ar = -expf(Arl[i]), ai = Aim[i];
            float dr = dt * ar, di = dt * ai;
            drs[n] = dr; dis[n] = di;
            float e = expf(dr);
            float wr = e * cosf(di), wi = e * sinf(di);
            float em1r = wr - 1.0f, em1i = wi;
            float Crv = Cr[i], Civ = Ci[i];
            float tr = Crv * em1r - Civ * em1i;
            float ti = Crv * em1i + Civ * em1r;
            float inv = 1.0f / (ar * ar + ai * ai);
            c2rs[n] = 2.0f * (tr * ar + ti * ai) * inv;
            c2is[n] = 2.0f * (ti * ar - tr * ai) * inv;
            // w^64 for the chunk-scan carry
            float jf = 64.0f;
            float er64 = expf(jf * dr);
            float ph64 = jf * di;
            wT[h * 64 + n] = make_float2(er64 * cosf(ph64), er64 * sinf(ph64));
        }
        __syncthreads();
        // kv[j] = sum_n c2r*Re(w^j) - c2i*Im(w^j), partial sums per 16-n part
        {
            int j = t & 63, part = t >> 6;
            float jf = (float)j;
            float s = 0.0f;
            for (int nn = part * 16; nn < part * 16 + 16; ++nn) {
                float er = expf(jf * drs[nn]);
                float ph = jf * dis[nn];
                float wr = er * cosf(ph), wi = er * sinf(ph);
                s += c2rs[nn] * wr - c2is[nn] * wi;
            }
            kp[part][j] = s;
        }
        __syncthreads();
        if (t < 64) kv[t] = kp[0][t] + kp[1][t] + kp[2][t] + kp[3][t];
        __syncthreads();
        // Bt rows 0..63: causal lower-triangular kernel
#pragma unroll
        for (int it = 0; it < 16; ++it) {
            int id3 = it * 256 + t, row = id3 >> 6, col = id3 & 63;
            int d = row - col;
            float v = (d >= 0) ? kv[d] : 0.0f;
            Bt[(size_t)(h * 192 + row) * 64 + col] = __float2bfloat16(v);
        }
        // Bt rows 64..191: w^(63-j) powers, rows 64+2n (Re) / 64+2n+1 (Im)
#pragma unroll
        for (int it = 0; it < 16; ++it) {
            int id3 = it * 256 + t;
            int n = id3 >> 6, j = id3 & 63;
            float jf = (float)(63 - j);
            float er = expf(jf * drs[n]);
            float ph = jf * dis[n];
            float wr = er * cosf(ph), wi = er * sinf(ph);
            Bt[(size_t)(h * 192 + 64 + 2 * n) * 64 + j]     = __float2bfloat16(wr);
            Bt[(size_t)(h * 192 + 64 + 2 * n + 1) * 64 + j] = __float2bfloat16(wi);
        }
        // Qt: row trow, col pair (2n, 2n+1) = (Re, -Im) of c2 * w^(trow+1)
#pragma unroll
        for (int it = 0; it < 16; ++it) {
            int id3 = it * 256 + t;
            int trow = id3 >> 6, n = id3 & 63;
            float jf = (float)(trow + 1);
            float er = expf(jf * drs[n]);
            float ph = jf * dis[n];
            float wr = er * cosf(ph), wi = er * sinf(ph);
            float cR = c2rs[n] * wr - c2is[n] * wi;
            float cI = c2rs[n] * wi + c2is[n] * wr;
            __hip_bfloat16* qp = Qt + (size_t)(h * 64 + trow) * 128 + 2 * n;
            qp[0] = __float2bfloat16(cR);
            qp[1] = __float2bfloat16(-cI);
        }
    }
}

// ---------------------------------------------------------------------------
// K2: fused chunked SSM (M=64 rows = 4 batches, 48K LDS, 3 blocks/CU).
// ---------------------------------------------------------------------------
__global__ __launch_bounds__(256, 3) void chunk_scan(
        const __hip_bfloat16* __restrict__ xTb, const char* __restrict__ Btg,
        const char* __restrict__ Qtg, const float2* __restrict__ wTg,
        const float* __restrict__ Dv, __hip_bfloat16* __restrict__ yTa) {
    __shared__ char lds[49152];
    char* sX = lds;              // [64][128B]
    char* sB = lds + 8192;       // [192][128B]
    char* sS = lds;              // [64 rows][512B] f32, post-GEMM1 overlay
    char* sQ = lds + 32768;      // [64][256B]

    int tid = threadIdx.x, wv = tid >> 6, lane = tid & 63;
    int lm = lane & 15, q = lane >> 4, r8 = lane >> 3, c8 = lane & 7;
    // XCD-aware decode: h = (idx>>5)*8 + (idx&7); member m = (idx>>3)&3
    int idx = blockIdx.x;
    int h  = ((idx >> 5) << 3) | (idx & 7);
    int b0 = ((idx >> 3) & 3) * 4;

    int csrc = c8 ^ r8;
    // ---- stage sB: 24 wave-loads of 8 rows x 128B ----
#pragma unroll
    for (int j = 0; j < 6; ++j) {
        int i = wv * 6 + j;
        gll16(Btg + ((size_t)(h * 192 + i * 8 + r8)) * 128 + csrc * 16,
              sB + i * 1024);
    }
    // ---- stage sQ: 16 wave-loads of 4 rows x 256B ----
    {
        int r4 = lane >> 4, c16 = lane & 15;
#pragma unroll
        for (int j = 0; j < 4; ++j) {
            int i = wv * 4 + j;
            gll16(Qtg + (size_t)(h * 64 + i * 4 + r4) * 256 + (c16 ^ r4) * 16,
                  sQ + i * 1024);
        }
    }
    // ---- stage sX via gll16: 8 groups of 8 rows x 128B, 2 per wave ----
    {
        const char* xb = (const char*)xTb;
#pragma unroll
        for (int j = 0; j < 2; ++j) {
            int i = wv * 2 + j;                      // row group
            int bp = b0 + (i >> 1);                  // batch of this group
            int ch = (i & 1) * 8 + r8;               // chunk index (row&15)
            gll16(xb + ((size_t)(bp * H_ + h)) * 2048 + ch * 128 + csrc * 16,
                  sX + i * 1024);
        }
    }
    __syncthreads();

    // ---- GEMM1: wave rows wv*16+lm, N=192 (12 tiles), K=64 ----
    f32x4 acc[12];
#pragma unroll
    for (int nt = 0; nt < 12; ++nt) acc[nt] = (f32x4){0.f, 0.f, 0.f, 0.f};
#pragma unroll
    for (int kk = 0; kk < 2; ++kk) {
        int clog = kk * 4 + q;
        int m = wv * 16 + lm;
        bf16x8 af = *(const bf16x8*)(sX + m * 128 + ((clog ^ (m & 7)) * 16));
#pragma unroll
        for (int nt = 0; nt < 12; ++nt) {
            int nrow = nt * 16 + lm;
            bf16x8 bf = *(const bf16x8*)(sB + nrow * 128 + ((clog ^ (nrow & 7)) * 16));
            acc[nt] = __builtin_amdgcn_mfma_f32_16x16x32_bf16(
                af, bf, acc[nt], 0, 0, 0);
        }
    }
    __syncthreads();   // everyone done with sX/sB -> sS overlay is safe

    // ---- write Sloc (nt 4..11 -> ri 0..127) into sS f32 swizzled ----
#pragma unroll
    for (int nt = 4; nt < 12; ++nt) {
        int ri = (nt - 4) * 16 + lm;
#pragma unroll
        for (int r = 0; r < 4; ++r) {
            int row = wv * 16 + q * 4 + r;
            *(float*)(sS + row * 512 + (((ri >> 2) ^ (row & 7)) * 16)
                      + (ri & 3) * 4) = acc[nt][r];
        }
    }
    __syncthreads();

    // ---- serial chunk scan: one chain per thread (n = tid&63, bp = wv) ----
    {
        int n = tid & 63, bp = tid >> 6;
        float2 wt = wTg[h * 64 + n];             // w^64
        float sr = 0.0f, si = 0.0f;
#pragma unroll 1
        for (int c = 0; c < 16; ++c) {
            int row = bp * 16 + c;
            char* p = sS + row * 512 + (((n >> 1) ^ (row & 7)) * 16)
                      + (n & 1) * 8;
            float2 loc = *(float2*)p;
            *(float2*)p = make_float2(sr, si);   // S_in before update
            float nr2 = wt.x * sr - wt.y * si + loc.x;
            float ni2 = wt.x * si + wt.y * sr + loc.y;
            sr = nr2; si = ni2;
        }
    }
    __syncthreads();

    // ---- GEMM2: y += S_in[64 x 128] * Qt^T, K=128 (4 k-steps) ----
#pragma unroll
    for (int ks = 0; ks < 4; ++ks) {
        int row = wv * 16 + lm;
        int cf0 = ks * 8 + q * 2;
        f32x4 a0 = *(const f32x4*)(sS + row * 512 + ((cf0 ^ (row & 7)) * 16));
        f32x4 a1 = *(const f32x4*)(sS + row * 512 + (((cf0 + 1) ^ (row & 7)) * 16));
        bf16x8 af;
        af[0] = (__bf16)a0[0]; af[1] = (__bf16)a0[1];
        af[2] = (__bf16)a0[2]; af[3] = (__bf16)a0[3];
        af[4] = (__bf16)a1[0]; af[5] = (__bf16)a1[1];
        af[6] = (__bf16)a1[2]; af[7] = (__bf16)a1[3];
#pragma unroll
        for (int nt = 0; nt < 4; ++nt) {
            int trow = nt * 16 + lm;
            int clog = ks * 4 + q;
            bf16x8 bq = *(const bf16x8*)(sQ + trow * 256 + ((clog ^ (trow & 3)) * 16));
            acc[nt] = __builtin_amdgcn_mfma_f32_16x16x32_bf16(
                af, bq, acc[nt], 0, 0, 0);
        }
    }

    // ---- epilogue: D-skip (bf16 x) + GELU -> yTa ----
    float Dh = Dv[h];
#pragma unroll
    for (int nt = 0; nt < 4; ++nt)
#pragma unroll
        for (int r = 0; r < 4; ++r) {
            int row = wv * 16 + q * 4 + r;
            int seq = (b0 + (row >> 4)) * H_ + h;
            int l   = (row & 15) * 64 + nt * 16 + lm;
            float xv = __bfloat162float(xTb[(size_t)seq * L_ + l]);
            float yv = acc[nt][r] + xv * Dh;
            yTa[(size_t)seq * L_ + l] = __float2bfloat16(gelu_tanh(yv));
        }
}

// ---------------------------------------------------------------------------
// K4: Z = Y @ Wt^T (+b), fused GLU epilogue.
// A-operand read DIRECTLY from yTa = Y^T [B*H, L] via ds_read_b64_tr_b16:
// transpose_y kernel and the Ybf round-trip (64MB) are eliminated.
// sA LDS layout (16KB per kt, K-tile=64, M-tile=128):
//   byte(k,m) = (k>>2)*1024 + (m>>4)*128 + (k&3)*32 + (m&15)*2
//   -> [K/4][M/16][4k][16m] subtiles (T10-prescribed format).
// tr16 read: lane addr = subtile_base + (lane&15)*8 (its 64b slot); HW
// delivers column (lane&15): elem j = subtile[k=j][m=lane&15].
// Staged linearly by gll16: issue kq covers k-rows kq*4..kq*4+3, each row
// read as 256B contiguous from yTa (coalesced).
// ---------------------------------------------------------------------------
__global__ __launch_bounds__(256, 3) void gemm_glu(
        const __hip_bfloat16* __restrict__ Yt, const __hip_bfloat16* __restrict__ Wt,
        const float* __restrict__ bv, float* __restrict__ out) {
    __shared__ char lds[32768];
    char* sA  = lds;             // A^T tile, subtiled, 16 KiB
    char* sBa = lds + 16384;     // [64][128B] = 8 KiB
    char* sBg = lds + 24576;     // [64][128B] = 8 KiB

    int tid = threadIdx.x, wv = tid >> 6, lane = tid & 63;
    int mb = (blockIdx.x & 127) * 128;
    int h0 = (blockIdx.x >> 7) * 64;
    int bA = mb >> 10;           // batch of this M-tile (128 | 1024)
    int l0 = mb & 1023;          // sequence-pos base
    int r8 = lane >> 3, c8 = lane & 7, csrc = c8 ^ r8;
    int wm = (wv >> 1) * 64, wn = (wv & 1) * 32;
    int lm = lane & 15, q = lane >> 4;

    // A-staging per-lane decode: issue kq -> k = kq*4 + kA, m-offset mA
    int kA = (lane >> 1) & 3;
    int mA = (lane >> 3) * 16 + (lane & 1) * 8;

    const char* Yb = (const char*)Yt;
    const char* Wb = (const char*)Wt;
    unsigned aBase = (unsigned)(size_t)sA;

    f32x4 accA[4][2], accG[4][2];
#pragma unroll
    for (int i = 0; i < 4; ++i)
#pragma unroll
        for (int j = 0; j < 2; ++j) {
            accA[i][j] = (f32x4){0.f, 0.f, 0.f, 0.f};
            accG[i][j] = (f32x4){0.f, 0.f, 0.f, 0.f};
        }

    for (int kt = 0; kt < 16; ++kt) {
        int k0b = kt * 128;      // byte offset into Wt rows
        __syncthreads();
        // ---- stage A^T: 16 issues of 1KB (4 per wave) ----
#pragma unroll
        for (int j = 0; j < 4; ++j) {
            int kq = wv * 4 + j;
            gll16(Yb + ((size_t)(bA * H_ + kt * 64 + kq * 4 + kA)) * 2048
                      + (size_t)(l0 + mA) * 2,
                  sA + kq * 1024);
        }
        // ---- stage Ba/Bg from Wt rows ----
#pragma unroll
        for (int j = 0; j < 2; ++j) {
            int i = wv * 2 + j;
            int n = h0 + i * 8 + r8;
            gll16(Wb + (size_t)n * 2048 + k0b + csrc * 16, sBa + i * 1024);
            gll16(Wb + (size_t)(n + 1024) * 2048 + k0b + csrc * 16, sBg + i * 1024);
        }
        __syncthreads();
#pragma unroll
        for (int kk = 0; kk < 2; ++kk) {
            int clog = kk * 4 + q;   // k-octet index for this lane-quad
            // ---- A-fragments: 2 tr reads per mt, lane slot = lm*8 ----
            unsigned long long r0[4], r1[4];
#pragma unroll
            for (int mt = 0; mt < 4; ++mt) {
                unsigned a0 = aBase + (unsigned)(clog * 2048
                               + ((wm >> 4) + mt) * 128 + lm * 8);
                r0[mt] = tr16(a0);
                r1[mt] = tr16(a0 + 1024);
            }
            // ---- B-fragments (compiler-managed ds_read_b128) ----
            bf16x8 ba[2], bg[2];
#pragma unroll
            for (int nt = 0; nt < 2; ++nt) {
                int n = wn + nt * 16 + lm;
                int cph = (clog ^ (n & 7)) * 16;
                ba[nt] = *(const bf16x8*)(sBa + n * 128 + cph);
                bg[nt] = *(const bf16x8*)(sBg + n * 128 + cph);
            }
            // tr results are untracked by the compiler: drain + fence (rule 18)
            asm volatile("s_waitcnt lgkmcnt(0)" ::: "memory");
            __builtin_amdgcn_sched_barrier(0);
#pragma unroll
            for (int mt = 0; mt < 4; ++mt) {
                union { unsigned long long u[2]; bf16x8 v; } cv;
                cv.u[0] = r0[mt]; cv.u[1] = r1[mt];
                bf16x8 af = cv.v;
#pragma unroll
                for (int nt = 0; nt < 2; ++nt) {
                    accA[mt][nt] = __builtin_amdgcn_mfma_f32_16x16x32_bf16(
                        af, ba[nt], accA[mt][nt], 0, 0, 0);
                    accG[mt][nt] = __builtin_amdgcn_mfma_f32_16x16x32_bf16(
                        af, bg[nt], accG[mt][nt], 0, 0, 0);
                }
            }
        }
    }
#pragma unroll
    for (int mt = 0; mt < 4; ++mt)
#pragma unroll
        for (int nt = 0; nt < 2; ++nt) {
            int hc = h0 + wn + nt * 16 + lm;
            float bba = bv[hc], bbg = bv[hc + 1024];
#pragma unroll
            for (int r = 0; r < 4; ++r) {
                int m = mb + wm + mt * 16 + q * 4 + r;
                float za = accA[mt][nt][r] + bba;
                float zg = accG[mt][nt][r] + bbg;
                out[(size_t)m * H_ + hc] = za / (1.0f + expf(-zg));
            }
        }
}

// ---------------------------------------------------------------------------
extern "C" void kernel_launch(void* const* d_in, const int* in_sizes, int n_in,
                              void* d_out, int out_size, void* d_ws, size_t ws_size,
                              hipStream_t stream) {
    const float* x      = (const float*)d_in[0];
    const float* log_dt = (const float*)d_in[1];
    const float* Arl    = (const float*)d_in[2];
    const float* Aim    = (const float*)d_in[3];
    const float* Cr     = (const float*)d_in[4];
    const float* Ci     = (const float*)d_in[5];
    const float* Dv     = (const float*)d_in[6];
    const float* W      = (const float*)d_in[7];
    const float* bv     = (const float*)d_in[8];
    float* out = (float*)d_out;

    char* ws = (char*)d_ws;
    // layout:
    //   [0,  32M) xTb bf16
    //   [32M,64M) yTa bf16 (consumed directly by gemm_glu as A^T)
    //   [64M,88M) Bt | [88M,104M) Qt | [104M,104.5M) wT | [105M,109M) Wt
    __hip_bfloat16*  xTb = (__hip_bfloat16*)ws;
    __hip_bfloat16*  yTa = (__hip_bfloat16*)(ws + (32u << 20));
    char*            Btg = ws + (64u << 20);
    char*            Qtg = Btg + (size_t)H_ * 192 * 64 * 2;          // +24M
    float2*          wTg = (float2*)(ws + (104u << 20));
    __hip_bfloat16*  Wt  = (__hip_bfloat16*)(ws + (105u << 20));

    prep<<<2176, 256, 0, stream>>>(x, log_dt, Arl, Aim, Cr, Ci, W,
                                   xTb, (__hip_bfloat16*)Btg,
                                   (__hip_bfloat16*)Qtg, wTg, Wt);
    chunk_scan<<<4096, 256, 0, stream>>>(xTb, Btg, Qtg, wTg, Dv, yTa);
    gemm_glu<<<2048, 256, 0, stream>>>(yTa, Wt, bv, out);
}

// Round 6
// 300.682 us; speedup vs baseline: 1.0796x; 1.0248x over previous
//
#include <hip/hip_runtime.h>
#include <hip/hip_bf16.h>

// Problem constants
#define B_ 16
#define L_ 1024
#define H_ 1024
#define N_ 64
// M = B*L = 16384, K = H = 1024, output cols = 2H = 2048 (a|g pairs)
// Chunked SSM: T=64 chunk, 16 chunks/seq.

typedef __bf16 bf16x8 __attribute__((ext_vector_type(8)));
typedef float  f32x4  __attribute__((ext_vector_type(4)));
typedef unsigned short u16x4 __attribute__((ext_vector_type(4)));
typedef unsigned short u16x8 __attribute__((ext_vector_type(8)));

// async global->LDS, 16B per lane; LDS dest is wave-uniform base + lane*16
__device__ __forceinline__ void gll16(const void* g, void* l) {
    __builtin_amdgcn_global_load_lds(
        (const __attribute__((address_space(1))) unsigned int*)g,
        (__attribute__((address_space(3))) unsigned int*)l,
        16, 0, 0);
}

// hardware transpose-read. Semantics (HW-verified round 4):
// lane supplies the address of ITS 64-bit slot; HW forms the 128B-aligned
// window W = addr & ~127, slot i = (addr>>3)&15, and delivers the 4 bf16 at
// bytes W + i*2 + j*32 (j=0..3) — i.e. column i of the window viewed as a
// [4][16] row-major bf16 subtile. Correct usage: addr = subtile_base + lm*8.
__device__ __forceinline__ unsigned long long tr16(unsigned a) {
    unsigned long long d;
    asm volatile("ds_read_b64_tr_b16 %0, %1" : "=v"(d) : "v"(a));
    return d;
}

__device__ __forceinline__ float gelu_tanh(float yv) {
    float u = yv + 0.044715f * yv * yv * yv;
    return 0.5f * yv * (1.0f + tanhf(0.7978845608028654f * u));
}

// ---------------------------------------------------------------------------
// K0 "prep": one kernel, 2176 blocks x 256 threads.
//  [0,1024):    x [B,L,H] f32 -> xTb [B*H, L] bf16 — LDS-staged transpose:
//               coalesced 1KB row reads -> swizzled 32KB LDS tile ->
//               coalesced 128B row writes. Swizzle: byte-col ^= (r>>3)<<4;
//               phase-B banks = (r8l>>1) | ((c8l^k)<<2) -> all 32, 2-way free.
//  [1024,1152): W [1024,2048] f32 -> Wt [2048,1024] bf16 (same scheme)
//  [1152,2176): build_tables (Bt/Qt/wT), one h per block (sm[0..2304) only)
// ---------------------------------------------------------------------------
__global__ __launch_bounds__(256) void prep(
        const float* __restrict__ x, const float* __restrict__ log_dt,
        const float* __restrict__ Arl, const float* __restrict__ Aim,
        const float* __restrict__ Cr, const float* __restrict__ Ci,
        const float* __restrict__ W,
        __hip_bfloat16* __restrict__ xTb, __hip_bfloat16* __restrict__ Bt,
        __hip_bfloat16* __restrict__ Qt, float2* __restrict__ wT,
        __hip_bfloat16* __restrict__ Wt) {
    __shared__ char sm[32768];
    int idx = blockIdx.x, t = threadIdx.x;
    int wv = t >> 6, lane = t & 63;

    if (idx < 1152) {
        // ---- transpose (x or W): 64 rows x 256 cols f32 -> bf16 ----
        const float* src;            // input tile base (row 0, col 0)
        size_t in_stride;            // input row stride (floats)
        unsigned short* dst;         // output tile base (row 0, col 0)
        size_t out_stride;           // output row stride (elems)
        if (idx < 1024) {
            int b = idx >> 6, lt = (idx >> 2) & 15, ht = idx & 3;
            int l0 = lt * 64, hb0 = ht * 256;
            src = x + ((size_t)b * L_ + l0) * H_ + hb0;
            in_stride = H_;
            dst = (unsigned short*)xTb + ((size_t)b * H_ + hb0) * L_ + l0;
            out_stride = L_;
        } else {
            int id2 = idx - 1024;
            int kt = id2 >> 3, ntile = id2 & 7;
            int k0 = kt * 64, nb0 = ntile * 256;
            src = W + (size_t)k0 * 2048 + nb0;
            in_stride = 2048;
            dst = (unsigned short*)Wt + (size_t)nb0 * H_ + k0;
            out_stride = H_;
        }
        // phase A: row r = j*4+wv, lane covers 4 cols -> 8B swizzled LDS write
#pragma unroll
        for (int j = 0; j < 16; ++j) {
            int r = j * 4 + wv;
            float4 v = *(const float4*)(src + (size_t)r * in_stride + lane * 4);
            __hip_bfloat16 h0 = __float2bfloat16(v.x), h1 = __float2bfloat16(v.y),
                           h2 = __float2bfloat16(v.z), h3 = __float2bfloat16(v.w);
            u16x4 pk;
            pk[0] = *(unsigned short*)&h0; pk[1] = *(unsigned short*)&h1;
            pk[2] = *(unsigned short*)&h2; pk[3] = *(unsigned short*)&h3;
            *(u16x4*)(sm + r * 512 + ((lane * 8) ^ (((r >> 3) & 7) << 4))) = pk;
        }
        __syncthreads();
        // phase B: out row hh = i*32+wv*8+r8, lane's c8 picks 8-col chunk
        {
            int r8l = lane >> 3, c8l = lane & 7;
            int swz = c8l << 4;          // (r>>3)&7 == c8l for r = c8l*8+k
#pragma unroll
            for (int i = 0; i < 8; ++i) {
                int hh = i * 32 + wv * 8 + r8l;
                u16x8 o;
#pragma unroll
                for (int k = 0; k < 8; ++k) {
                    int r = c8l * 8 + k;
                    o[k] = *(unsigned short*)(sm + r * 512 + ((hh * 2) ^ swz));
                }
                *(u16x8*)(dst + (size_t)hh * out_stride + c8l * 8) = o;
            }
        }
        return;
    }
    // ---- build_tables: h = idx - 1152 ----
    {
        float* drs  = (float*)sm;            // [64]
        float* dis  = (float*)(sm + 256);    // [64]
        float* c2rs = (float*)(sm + 512);    // [64]
        float* c2is = (float*)(sm + 768);    // [64]
        float (*kp)[64] = (float(*)[64])(sm + 1024);  // [4][64]
        float* kv   = (float*)(sm + 2048);   // [64]
        int h = idx - 1152;

        if (t < 64) {
            int n = t, i = h * 64 + n;
            float dt = expf(log_dt[h]);
            float ar = -expf(Arl[i]), ai = Aim[i];
            float dr = dt * ar, di = dt * ai;
            drs[n] = dr; dis[n] = di;
            float e = expf(dr);
            float wr = e * cosf(di), wi = e * sinf(di);
            float em1r = wr - 1.0f, em1i = wi;
            float Crv = Cr[i], Civ = Ci[i];
            float tr = Crv * em1r - Civ * em1i;
            float ti = Crv * em1i + Civ * em1r;
            float inv = 1.0f / (ar * ar + ai * ai);
            c2rs[n] = 2.0f * (tr * ar + ti * ai) * inv;
            c2is[n] = 2.0f * (ti * ar - tr * ai) * inv;
            // w^64 for the chunk-scan carry
            float jf = 64.0f;
            float er64 = expf(jf * dr);
            float ph64 = jf * di;
            wT[h * 64 + n] = make_float2(er64 * cosf(ph64), er64 * sinf(ph64));
        }
        __syncthreads();
        // kv[j] = sum_n c2r*Re(w^j) - c2i*Im(w^j), partial sums per 16-n part
        {
            int j = t & 63, part = t >> 6;
            float jf = (float)j;
            float s = 0.0f;
            for (int nn = part * 16; nn < part * 16 + 16; ++nn) {
                float er = expf(jf * drs[nn]);
                float ph = jf * dis[nn];
                float wr = er * cosf(ph), wi = er * sinf(ph);
                s += c2rs[nn] * wr - c2is[nn] * wi;
            }
            kp[part][j] = s;
        }
        __syncthreads();
        if (t < 64) kv[t] = kp[0][t] + kp[1][t] + kp[2][t] + kp[3][t];
        __syncthreads();
        // Bt rows 0..63: causal lower-triangular kernel
#pragma unroll
        for (int it = 0; it < 16; ++it) {
            int id3 = it * 256 + t, row = id3 >> 6, col = id3 & 63;
            int d = row - col;
            float v = (d >= 0) ? kv[d] : 0.0f;
            Bt[(size_t)(h * 192 + row) * 64 + col] = __float2bfloat16(v);
        }
        // Bt rows 64..191: w^(63-j) powers, rows 64+2n (Re) / 64+2n+1 (Im)
#pragma unroll
        for (int it = 0; it < 16; ++it) {
            int id3 = it * 256 + t;
            int n = id3 >> 6, j = id3 & 63;
            float jf = (float)(63 - j);
            float er = expf(jf * drs[n]);
            float ph = jf * dis[n];
            float wr = er * cosf(ph), wi = er * sinf(ph);
            Bt[(size_t)(h * 192 + 64 + 2 * n) * 64 + j]     = __float2bfloat16(wr);
            Bt[(size_t)(h * 192 + 64 + 2 * n + 1) * 64 + j] = __float2bfloat16(wi);
        }
        // Qt: row trow, col pair (2n, 2n+1) = (Re, -Im) of c2 * w^(trow+1)
#pragma unroll
        for (int it = 0; it < 16; ++it) {
            int id3 = it * 256 + t;
            int trow = id3 >> 6, n = id3 & 63;
            float jf = (float)(trow + 1);
            float er = expf(jf * drs[n]);
            float ph = jf * dis[n];
            float wr = er * cosf(ph), wi = er * sinf(ph);
            float cR = c2rs[n] * wr - c2is[n] * wi;
            float cI = c2rs[n] * wi + c2is[n] * wr;
            __hip_bfloat16* qp = Qt + (size_t)(h * 64 + trow) * 128 + 2 * n;
            qp[0] = __float2bfloat16(cR);
            qp[1] = __float2bfloat16(-cI);
        }
    }
}

// ---------------------------------------------------------------------------
// K2: fused chunked SSM (M=64 rows = 4 batches, 48K LDS, 3 blocks/CU).
// ---------------------------------------------------------------------------
__global__ __launch_bounds__(256, 3) void chunk_scan(
        const __hip_bfloat16* __restrict__ xTb, const char* __restrict__ Btg,
        const char* __restrict__ Qtg, const float2* __restrict__ wTg,
        const float* __restrict__ Dv, __hip_bfloat16* __restrict__ yTa) {
    __shared__ char lds[49152];
    char* sX = lds;              // [64][128B]
    char* sB = lds + 8192;       // [192][128B]
    char* sS = lds;              // [64 rows][512B] f32, post-GEMM1 overlay
    char* sQ = lds + 32768;      // [64][256B]

    int tid = threadIdx.x, wv = tid >> 6, lane = tid & 63;
    int lm = lane & 15, q = lane >> 4, r8 = lane >> 3, c8 = lane & 7;
    // XCD-aware decode: h = (idx>>5)*8 + (idx&7); member m = (idx>>3)&3
    int idx = blockIdx.x;
    int h  = ((idx >> 5) << 3) | (idx & 7);
    int b0 = ((idx >> 3) & 3) * 4;

    int csrc = c8 ^ r8;
    // ---- stage sB: 24 wave-loads of 8 rows x 128B ----
#pragma unroll
    for (int j = 0; j < 6; ++j) {
        int i = wv * 6 + j;
        gll16(Btg + ((size_t)(h * 192 + i * 8 + r8)) * 128 + csrc * 16,
              sB + i * 1024);
    }
    // ---- stage sQ: 16 wave-loads of 4 rows x 256B ----
    {
        int r4 = lane >> 4, c16 = lane & 15;
#pragma unroll
        for (int j = 0; j < 4; ++j) {
            int i = wv * 4 + j;
            gll16(Qtg + (size_t)(h * 64 + i * 4 + r4) * 256 + (c16 ^ r4) * 16,
                  sQ + i * 1024);
        }
    }
    // ---- stage sX via gll16: 8 groups of 8 rows x 128B, 2 per wave ----
    {
        const char* xb = (const char*)xTb;
#pragma unroll
        for (int j = 0; j < 2; ++j) {
            int i = wv * 2 + j;                      // row group
            int bp = b0 + (i >> 1);                  // batch of this group
            int ch = (i & 1) * 8 + r8;               // chunk index (row&15)
            gll16(xb + ((size_t)(bp * H_ + h)) * 2048 + ch * 128 + csrc * 16,
                  sX + i * 1024);
        }
    }
    __syncthreads();

    // ---- GEMM1: wave rows wv*16+lm, N=192 (12 tiles), K=64 ----
    f32x4 acc[12];
#pragma unroll
    for (int nt = 0; nt < 12; ++nt) acc[nt] = (f32x4){0.f, 0.f, 0.f, 0.f};
#pragma unroll
    for (int kk = 0; kk < 2; ++kk) {
        int clog = kk * 4 + q;
        int m = wv * 16 + lm;
        bf16x8 af = *(const bf16x8*)(sX + m * 128 + ((clog ^ (m & 7)) * 16));
#pragma unroll
        for (int nt = 0; nt < 12; ++nt) {
            int nrow = nt * 16 + lm;
            bf16x8 bf = *(const bf16x8*)(sB + nrow * 128 + ((clog ^ (nrow & 7)) * 16));
            acc[nt] = __builtin_amdgcn_mfma_f32_16x16x32_bf16(
                af, bf, acc[nt], 0, 0, 0);
        }
    }
    __syncthreads();   // everyone done with sX/sB -> sS overlay is safe

    // ---- write Sloc (nt 4..11 -> ri 0..127) into sS f32 swizzled ----
#pragma unroll
    for (int nt = 4; nt < 12; ++nt) {
        int ri = (nt - 4) * 16 + lm;
#pragma unroll
        for (int r = 0; r < 4; ++r) {
            int row = wv * 16 + q * 4 + r;
            *(float*)(sS + row * 512 + (((ri >> 2) ^ (row & 7)) * 16)
                      + (ri & 3) * 4) = acc[nt][r];
        }
    }
    __syncthreads();

    // ---- serial chunk scan: one chain per thread (n = tid&63, bp = wv) ----
    {
        int n = tid & 63, bp = tid >> 6;
        float2 wt = wTg[h * 64 + n];             // w^64
        float sr = 0.0f, si = 0.0f;
#pragma unroll 1
        for (int c = 0; c < 16; ++c) {
            int row = bp * 16 + c;
            char* p = sS + row * 512 + (((n >> 1) ^ (row & 7)) * 16)
                      + (n & 1) * 8;
            float2 loc = *(float2*)p;
            *(float2*)p = make_float2(sr, si);   // S_in before update
            float nr2 = wt.x * sr - wt.y * si + loc.x;
            float ni2 = wt.x * si + wt.y * sr + loc.y;
            sr = nr2; si = ni2;
        }
    }
    __syncthreads();

    // ---- GEMM2: y += S_in[64 x 128] * Qt^T, K=128 (4 k-steps) ----
#pragma unroll
    for (int ks = 0; ks < 4; ++ks) {
        int row = wv * 16 + lm;
        int cf0 = ks * 8 + q * 2;
        f32x4 a0 = *(const f32x4*)(sS + row * 512 + ((cf0 ^ (row & 7)) * 16));
        f32x4 a1 = *(const f32x4*)(sS + row * 512 + (((cf0 + 1) ^ (row & 7)) * 16));
        bf16x8 af;
        af[0] = (__bf16)a0[0]; af[1] = (__bf16)a0[1];
        af[2] = (__bf16)a0[2]; af[3] = (__bf16)a0[3];
        af[4] = (__bf16)a1[0]; af[5] = (__bf16)a1[1];
        af[6] = (__bf16)a1[2]; af[7] = (__bf16)a1[3];
#pragma unroll
        for (int nt = 0; nt < 4; ++nt) {
            int trow = nt * 16 + lm;
            int clog = ks * 4 + q;
            bf16x8 bq = *(const bf16x8*)(sQ + trow * 256 + ((clog ^ (trow & 3)) * 16));
            acc[nt] = __builtin_amdgcn_mfma_f32_16x16x32_bf16(
                af, bq, acc[nt], 0, 0, 0);
        }
    }

    // ---- epilogue: D-skip (bf16 x) + GELU -> yTa ----
    float Dh = Dv[h];
#pragma unroll
    for (int nt = 0; nt < 4; ++nt)
#pragma unroll
        for (int r = 0; r < 4; ++r) {
            int row = wv * 16 + q * 4 + r;
            int seq = (b0 + (row >> 4)) * H_ + h;
            int l   = (row & 15) * 64 + nt * 16 + lm;
            float xv = __bfloat162float(xTb[(size_t)seq * L_ + l]);
            float yv = acc[nt][r] + xv * Dh;
            yTa[(size_t)seq * L_ + l] = __float2bfloat16(gelu_tanh(yv));
        }
}

// ---------------------------------------------------------------------------
// K4: Z = Y @ Wt^T (+b), fused GLU epilogue.
// A-operand read DIRECTLY from yTa = Y^T [B*H, L] via ds_read_b64_tr_b16:
// transpose_y kernel and the Ybf round-trip (64MB) are eliminated.
// sA LDS layout (16KB per kt, K-tile=64, M-tile=128):
//   byte(k,m) = (k>>2)*1024 + (m>>4)*128 + (k&3)*32 + (m&15)*2
//   -> [K/4][M/16][4k][16m] subtiles (T10-prescribed format).
// tr16 read: lane addr = subtile_base + (lane&15)*8 (its 64b slot); HW
// delivers column (lane&15): elem j = subtile[k=j][m=lane&15].
// Staged linearly by gll16: issue kq covers k-rows kq*4..kq*4+3, each row
// read as 256B contiguous from yTa (coalesced).
// ---------------------------------------------------------------------------
__global__ __launch_bounds__(256, 3) void gemm_glu(
        const __hip_bfloat16* __restrict__ Yt, const __hip_bfloat16* __restrict__ Wt,
        const float* __restrict__ bv, float* __restrict__ out) {
    __shared__ char lds[32768];
    char* sA  = lds;             // A^T tile, subtiled, 16 KiB
    char* sBa = lds + 16384;     // [64][128B] = 8 KiB
    char* sBg = lds + 24576;     // [64][128B] = 8 KiB

    int tid = threadIdx.x, wv = tid >> 6, lane = tid & 63;
    int mb = (blockIdx.x & 127) * 128;
    int h0 = (blockIdx.x >> 7) * 64;
    int bA = mb >> 10;           // batch of this M-tile (128 | 1024)
    int l0 = mb & 1023;          // sequence-pos base
    int r8 = lane >> 3, c8 = lane & 7, csrc = c8 ^ r8;
    int wm = (wv >> 1) * 64, wn = (wv & 1) * 32;
    int lm = lane & 15, q = lane >> 4;

    // A-staging per-lane decode: issue kq -> k = kq*4 + kA, m-offset mA
    int kA = (lane >> 1) & 3;
    int mA = (lane >> 3) * 16 + (lane & 1) * 8;

    const char* Yb = (const char*)Yt;
    const char* Wb = (const char*)Wt;
    unsigned aBase = (unsigned)(size_t)sA;

    f32x4 accA[4][2], accG[4][2];
#pragma unroll
    for (int i = 0; i < 4; ++i)
#pragma unroll
        for (int j = 0; j < 2; ++j) {
            accA[i][j] = (f32x4){0.f, 0.f, 0.f, 0.f};
            accG[i][j] = (f32x4){0.f, 0.f, 0.f, 0.f};
        }

    for (int kt = 0; kt < 16; ++kt) {
        int k0b = kt * 128;      // byte offset into Wt rows
        __syncthreads();
        // ---- stage A^T: 16 issues of 1KB (4 per wave) ----
#pragma unroll
        for (int j = 0; j < 4; ++j) {
            int kq = wv * 4 + j;
            gll16(Yb + ((size_t)(bA * H_ + kt * 64 + kq * 4 + kA)) * 2048
                      + (size_t)(l0 + mA) * 2,
                  sA + kq * 1024);
        }
        // ---- stage Ba/Bg from Wt rows ----
#pragma unroll
        for (int j = 0; j < 2; ++j) {
            int i = wv * 2 + j;
            int n = h0 + i * 8 + r8;
            gll16(Wb + (size_t)n * 2048 + k0b + csrc * 16, sBa + i * 1024);
            gll16(Wb + (size_t)(n + 1024) * 2048 + k0b + csrc * 16, sBg + i * 1024);
        }
        __syncthreads();
#pragma unroll
        for (int kk = 0; kk < 2; ++kk) {
            int clog = kk * 4 + q;   // k-octet index for this lane-quad
            // ---- A-fragments: 2 tr reads per mt, lane slot = lm*8 ----
            unsigned long long r0[4], r1[4];
#pragma unroll
            for (int mt = 0; mt < 4; ++mt) {
                unsigned a0 = aBase + (unsigned)(clog * 2048
                               + ((wm >> 4) + mt) * 128 + lm * 8);
                r0[mt] = tr16(a0);
                r1[mt] = tr16(a0 + 1024);
            }
            // ---- B-fragments (compiler-managed ds_read_b128) ----
            bf16x8 ba[2], bg[2];
#pragma unroll
            for (int nt = 0; nt < 2; ++nt) {
                int n = wn + nt * 16 + lm;
                int cph = (clog ^ (n & 7)) * 16;
                ba[nt] = *(const bf16x8*)(sBa + n * 128 + cph);
                bg[nt] = *(const bf16x8*)(sBg + n * 128 + cph);
            }
            // tr results are untracked by the compiler: drain + fence (rule 18)
            asm volatile("s_waitcnt lgkmcnt(0)" ::: "memory");
            __builtin_amdgcn_sched_barrier(0);
#pragma unroll
            for (int mt = 0; mt < 4; ++mt) {
                union { unsigned long long u[2]; bf16x8 v; } cv;
                cv.u[0] = r0[mt]; cv.u[1] = r1[mt];
                bf16x8 af = cv.v;
#pragma unroll
                for (int nt = 0; nt < 2; ++nt) {
                    accA[mt][nt] = __builtin_amdgcn_mfma_f32_16x16x32_bf16(
                        af, ba[nt], accA[mt][nt], 0, 0, 0);
                    accG[mt][nt] = __builtin_amdgcn_mfma_f32_16x16x32_bf16(
                        af, bg[nt], accG[mt][nt], 0, 0, 0);
                }
            }
        }
    }
#pragma unroll
    for (int mt = 0; mt < 4; ++mt)
#pragma unroll
        for (int nt = 0; nt < 2; ++nt) {
            int hc = h0 + wn + nt * 16 + lm;
            float bba = bv[hc], bbg = bv[hc + 1024];
#pragma unroll
            for (int r = 0; r < 4; ++r) {
                int m = mb + wm + mt * 16 + q * 4 + r;
                float za = accA[mt][nt][r] + bba;
                float zg = accG[mt][nt][r] + bbg;
                out[(size_t)m * H_ + hc] = za / (1.0f + expf(-zg));
            }
        }
}

// ---------------------------------------------------------------------------
extern "C" void kernel_launch(void* const* d_in, const int* in_sizes, int n_in,
                              void* d_out, int out_size, void* d_ws, size_t ws_size,
                              hipStream_t stream) {
    const float* x      = (const float*)d_in[0];
    const float* log_dt = (const float*)d_in[1];
    const float* Arl    = (const float*)d_in[2];
    const float* Aim    = (const float*)d_in[3];
    const float* Cr     = (const float*)d_in[4];
    const float* Ci     = (const float*)d_in[5];
    const float* Dv     = (const float*)d_in[6];
    const float* W      = (const float*)d_in[7];
    const float* bv     = (const float*)d_in[8];
    float* out = (float*)d_out;

    char* ws = (char*)d_ws;
    // layout:
    //   [0,  32M) xTb bf16
    //   [32M,64M) yTa bf16 (consumed directly by gemm_glu as A^T)
    //   [64M,88M) Bt | [88M,104M) Qt | [104M,104.5M) wT | [105M,109M) Wt
    __hip_bfloat16*  xTb = (__hip_bfloat16*)ws;
    __hip_bfloat16*  yTa = (__hip_bfloat16*)(ws + (32u << 20));
    char*            Btg = ws + (64u << 20);
    char*            Qtg = Btg + (size_t)H_ * 192 * 64 * 2;          // +24M
    float2*          wTg = (float2*)(ws + (104u << 20));
    __hip_bfloat16*  Wt  = (__hip_bfloat16*)(ws + (105u << 20));

    prep<<<2176, 256, 0, stream>>>(x, log_dt, Arl, Aim, Cr, Ci, W,
                                   xTb, (__hip_bfloat16*)Btg,
                                   (__hip_bfloat16*)Qtg, wTg, Wt);
    chunk_scan<<<4096, 256, 0, stream>>>(xTb, Btg, Qtg, wTg, Dv, yTa);
    gemm_glu<<<2048, 256, 0, stream>>>(yTa, Wt, bv, out);
}

// Round 7
// 299.452 us; speedup vs baseline: 1.0840x; 1.0041x over previous
//
#include <hip/hip_runtime.h>
#include <hip/hip_bf16.h>

// Problem constants
#define B_ 16
#define L_ 1024
#define H_ 1024
#define N_ 64
// M = B*L = 16384, K = H = 1024, output cols = 2H = 2048 (a|g pairs)
// Chunked SSM: T=64 chunk, 16 chunks/seq.

typedef __bf16 bf16x8 __attribute__((ext_vector_type(8)));
typedef float  f32x4  __attribute__((ext_vector_type(4)));
typedef unsigned short u16x4 __attribute__((ext_vector_type(4)));
typedef unsigned short u16x8 __attribute__((ext_vector_type(8)));

// async global->LDS, 16B per lane; LDS dest is wave-uniform base + lane*16
__device__ __forceinline__ void gll16(const void* g, void* l) {
    __builtin_amdgcn_global_load_lds(
        (const __attribute__((address_space(1))) unsigned int*)g,
        (__attribute__((address_space(3))) unsigned int*)l,
        16, 0, 0);
}

// hardware transpose-read. Semantics (HW-verified round 4):
// lane supplies the address of ITS 64-bit slot; HW forms the 128B-aligned
// window W = addr & ~127, slot i = (addr>>3)&15, and delivers the 4 bf16 at
// bytes W + i*2 + j*32 (j=0..3) — i.e. column i of the window viewed as a
// [4][16] row-major bf16 subtile. Correct usage: addr = subtile_base + lm*8.
__device__ __forceinline__ unsigned long long tr16(unsigned a) {
    unsigned long long d;
    asm volatile("ds_read_b64_tr_b16 %0, %1" : "=v"(d) : "v"(a));
    return d;
}

__device__ __forceinline__ float gelu_tanh(float yv) {
    float u = yv + 0.044715f * yv * yv * yv;
    return 0.5f * yv * (1.0f + tanhf(0.7978845608028654f * u));
}

// ---------------------------------------------------------------------------
// K0 "prep": one kernel, 2176 blocks x 256 threads.
//  [0,1024):    x [B,L,H] f32 -> xTb [B*H, L] bf16 — LDS-staged transpose:
//               coalesced 1KB row reads -> swizzled 32KB LDS tile ->
//               coalesced 128B row writes. Swizzle: byte-col ^= (r>>3)<<4;
//               phase-B banks = (r8l>>1) | ((c8l^k)<<2) -> all 32, 2-way free.
//  [1024,1152): W [1024,2048] f32 -> Wt [2048,1024] bf16 (same scheme)
//  [1152,2176): build_tables (Bt/Qt/wT), one h per block (sm[0..2304) only)
// ---------------------------------------------------------------------------
__global__ __launch_bounds__(256) void prep(
        const float* __restrict__ x, const float* __restrict__ log_dt,
        const float* __restrict__ Arl, const float* __restrict__ Aim,
        const float* __restrict__ Cr, const float* __restrict__ Ci,
        const float* __restrict__ W,
        __hip_bfloat16* __restrict__ xTb, __hip_bfloat16* __restrict__ Bt,
        __hip_bfloat16* __restrict__ Qt, float2* __restrict__ wT,
        __hip_bfloat16* __restrict__ Wt) {
    __shared__ char sm[32768];
    int idx = blockIdx.x, t = threadIdx.x;
    int wv = t >> 6, lane = t & 63;

    if (idx < 1152) {
        // ---- transpose (x or W): 64 rows x 256 cols f32 -> bf16 ----
        const float* src;            // input tile base (row 0, col 0)
        size_t in_stride;            // input row stride (floats)
        unsigned short* dst;         // output tile base (row 0, col 0)
        size_t out_stride;           // output row stride (elems)
        if (idx < 1024) {
            int b = idx >> 6, lt = (idx >> 2) & 15, ht = idx & 3;
            int l0 = lt * 64, hb0 = ht * 256;
            src = x + ((size_t)b * L_ + l0) * H_ + hb0;
            in_stride = H_;
            dst = (unsigned short*)xTb + ((size_t)b * H_ + hb0) * L_ + l0;
            out_stride = L_;
        } else {
            int id2 = idx - 1024;
            int kt = id2 >> 3, ntile = id2 & 7;
            int k0 = kt * 64, nb0 = ntile * 256;
            src = W + (size_t)k0 * 2048 + nb0;
            in_stride = 2048;
            dst = (unsigned short*)Wt + (size_t)nb0 * H_ + k0;
            out_stride = H_;
        }
        // phase A: row r = j*4+wv, lane covers 4 cols -> 8B swizzled LDS write
#pragma unroll
        for (int j = 0; j < 16; ++j) {
            int r = j * 4 + wv;
            float4 v = *(const float4*)(src + (size_t)r * in_stride + lane * 4);
            __hip_bfloat16 h0 = __float2bfloat16(v.x), h1 = __float2bfloat16(v.y),
                           h2 = __float2bfloat16(v.z), h3 = __float2bfloat16(v.w);
            u16x4 pk;
            pk[0] = *(unsigned short*)&h0; pk[1] = *(unsigned short*)&h1;
            pk[2] = *(unsigned short*)&h2; pk[3] = *(unsigned short*)&h3;
            *(u16x4*)(sm + r * 512 + ((lane * 8) ^ (((r >> 3) & 7) << 4))) = pk;
        }
        __syncthreads();
        // phase B: out row hh = i*32+wv*8+r8, lane's c8 picks 8-col chunk
        {
            int r8l = lane >> 3, c8l = lane & 7;
            int swz = c8l << 4;          // (r>>3)&7 == c8l for r = c8l*8+k
#pragma unroll
            for (int i = 0; i < 8; ++i) {
                int hh = i * 32 + wv * 8 + r8l;
                u16x8 o;
#pragma unroll
                for (int k = 0; k < 8; ++k) {
                    int r = c8l * 8 + k;
                    o[k] = *(unsigned short*)(sm + r * 512 + ((hh * 2) ^ swz));
                }
                *(u16x8*)(dst + (size_t)hh * out_stride + c8l * 8) = o;
            }
        }
        return;
    }
    // ---- build_tables: h = idx - 1152 ----
    {
        float* drs  = (float*)sm;            // [64]
        float* dis  = (float*)(sm + 256);    // [64]
        float* c2rs = (float*)(sm + 512);    // [64]
        float* c2is = (float*)(sm + 768);    // [64]
        float (*kp)[64] = (float(*)[64])(sm + 1024);  // [4][64]
        float* kv   = (float*)(sm + 2048);   // [64]
        int h = idx - 1152;

        if (t < 64) {
            int n = t, i = h * 64 + n;
            float dt = expf(log_dt[h]);
            float ar = -expf(Arl[i]), ai = Aim[i];
            float dr = dt * ar, di = dt * ai;
            drs[n] = dr; dis[n] = di;
            float e = expf(dr);
            float wr = e * cosf(di), wi = e * sinf(di);
            float em1r = wr - 1.0f, em1i = wi;
            float Crv = Cr[i], Civ = Ci[i];
            float tr = Crv * em1r - Civ * em1i;
            float ti = Crv * em1i + Civ * em1r;
            float inv = 1.0f / (ar * ar + ai * ai);
            c2rs[n] = 2.0f * (tr * ar + ti * ai) * inv;
            c2is[n] = 2.0f * (ti * ar - tr * ai) * inv;
            // w^64 for the chunk-scan carry
            float jf = 64.0f;
            float er64 = expf(jf * dr);
            float ph64 = jf * di;
            wT[h * 64 + n] = make_float2(er64 * cosf(ph64), er64 * sinf(ph64));
        }
        __syncthreads();
        // kv[j] = sum_n c2r*Re(w^j) - c2i*Im(w^j), partial sums per 16-n part
        {
            int j = t & 63, part = t >> 6;
            float jf = (float)j;
            float s = 0.0f;
            for (int nn = part * 16; nn < part * 16 + 16; ++nn) {
                float er = expf(jf * drs[nn]);
                float ph = jf * dis[nn];
                float wr = er * cosf(ph), wi = er * sinf(ph);
                s += c2rs[nn] * wr - c2is[nn] * wi;
            }
            kp[part][j] = s;
        }
        __syncthreads();
        if (t < 64) kv[t] = kp[0][t] + kp[1][t] + kp[2][t] + kp[3][t];
        __syncthreads();
        // Bt rows 0..63: causal lower-triangular kernel
#pragma unroll
        for (int it = 0; it < 16; ++it) {
            int id3 = it * 256 + t, row = id3 >> 6, col = id3 & 63;
            int d = row - col;
            float v = (d >= 0) ? kv[d] : 0.0f;
            Bt[(size_t)(h * 192 + row) * 64 + col] = __float2bfloat16(v);
        }
        // Bt rows 64..191: w^(63-j) powers, rows 64+2n (Re) / 64+2n+1 (Im)
#pragma unroll
        for (int it = 0; it < 16; ++it) {
            int id3 = it * 256 + t;
            int n = id3 >> 6, j = id3 & 63;
            float jf = (float)(63 - j);
            float er = expf(jf * drs[n]);
            float ph = jf * dis[n];
            float wr = er * cosf(ph), wi = er * sinf(ph);
            Bt[(size_t)(h * 192 + 64 + 2 * n) * 64 + j]     = __float2bfloat16(wr);
            Bt[(size_t)(h * 192 + 64 + 2 * n + 1) * 64 + j] = __float2bfloat16(wi);
        }
        // Qt: row trow, col pair (2n, 2n+1) = (Re, -Im) of c2 * w^(trow+1)
#pragma unroll
        for (int it = 0; it < 16; ++it) {
            int id3 = it * 256 + t;
            int trow = id3 >> 6, n = id3 & 63;
            float jf = (float)(trow + 1);
            float er = expf(jf * drs[n]);
            float ph = jf * dis[n];
            float wr = er * cosf(ph), wi = er * sinf(ph);
            float cR = c2rs[n] * wr - c2is[n] * wi;
            float cI = c2rs[n] * wi + c2is[n] * wr;
            __hip_bfloat16* qp = Qt + (size_t)(h * 64 + trow) * 128 + 2 * n;
            qp[0] = __float2bfloat16(cR);
            qp[1] = __float2bfloat16(-cI);
        }
    }
}

// ---------------------------------------------------------------------------
// K2: fused chunked SSM (M=64 rows = 4 batches, 48K LDS, 3 blocks/CU).
// ---------------------------------------------------------------------------
__global__ __launch_bounds__(256, 3) void chunk_scan(
        const __hip_bfloat16* __restrict__ xTb, const char* __restrict__ Btg,
        const char* __restrict__ Qtg, const float2* __restrict__ wTg,
        const float* __restrict__ Dv, __hip_bfloat16* __restrict__ yTa) {
    __shared__ char lds[49152];
    char* sX = lds;              // [64][128B]
    char* sB = lds + 8192;       // [192][128B]
    char* sS = lds;              // [64 rows][512B] f32, post-GEMM1 overlay
    char* sQ = lds + 32768;      // [64][256B]

    int tid = threadIdx.x, wv = tid >> 6, lane = tid & 63;
    int lm = lane & 15, q = lane >> 4, r8 = lane >> 3, c8 = lane & 7;
    // XCD-aware decode: h = (idx>>5)*8 + (idx&7); member m = (idx>>3)&3
    int idx = blockIdx.x;
    int h  = ((idx >> 5) << 3) | (idx & 7);
    int b0 = ((idx >> 3) & 3) * 4;

    int csrc = c8 ^ r8;
    // ---- stage sB: 24 wave-loads of 8 rows x 128B ----
#pragma unroll
    for (int j = 0; j < 6; ++j) {
        int i = wv * 6 + j;
        gll16(Btg + ((size_t)(h * 192 + i * 8 + r8)) * 128 + csrc * 16,
              sB + i * 1024);
    }
    // ---- stage sQ: 16 wave-loads of 4 rows x 256B ----
    {
        int r4 = lane >> 4, c16 = lane & 15;
#pragma unroll
        for (int j = 0; j < 4; ++j) {
            int i = wv * 4 + j;
            gll16(Qtg + (size_t)(h * 64 + i * 4 + r4) * 256 + (c16 ^ r4) * 16,
                  sQ + i * 1024);
        }
    }
    // ---- stage sX via gll16: 8 groups of 8 rows x 128B, 2 per wave ----
    {
        const char* xb = (const char*)xTb;
#pragma unroll
        for (int j = 0; j < 2; ++j) {
            int i = wv * 2 + j;                      // row group
            int bp = b0 + (i >> 1);                  // batch of this group
            int ch = (i & 1) * 8 + r8;               // chunk index (row&15)
            gll16(xb + ((size_t)(bp * H_ + h)) * 2048 + ch * 128 + csrc * 16,
                  sX + i * 1024);
        }
    }
    __syncthreads();

    // ---- GEMM1: wave rows wv*16+lm, N=192 (12 tiles), K=64 ----
    f32x4 acc[12];
#pragma unroll
    for (int nt = 0; nt < 12; ++nt) acc[nt] = (f32x4){0.f, 0.f, 0.f, 0.f};
#pragma unroll
    for (int kk = 0; kk < 2; ++kk) {
        int clog = kk * 4 + q;
        int m = wv * 16 + lm;
        bf16x8 af = *(const bf16x8*)(sX + m * 128 + ((clog ^ (m & 7)) * 16));
#pragma unroll
        for (int nt = 0; nt < 12; ++nt) {
            int nrow = nt * 16 + lm;
            bf16x8 bf = *(const bf16x8*)(sB + nrow * 128 + ((clog ^ (nrow & 7)) * 16));
            acc[nt] = __builtin_amdgcn_mfma_f32_16x16x32_bf16(
                af, bf, acc[nt], 0, 0, 0);
        }
    }
    __syncthreads();   // everyone done with sX/sB -> sS overlay is safe

    // ---- write Sloc (nt 4..11 -> ri 0..127) into sS f32 swizzled ----
#pragma unroll
    for (int nt = 4; nt < 12; ++nt) {
        int ri = (nt - 4) * 16 + lm;
#pragma unroll
        for (int r = 0; r < 4; ++r) {
            int row = wv * 16 + q * 4 + r;
            *(float*)(sS + row * 512 + (((ri >> 2) ^ (row & 7)) * 16)
                      + (ri & 3) * 4) = acc[nt][r];
        }
    }
    __syncthreads();

    // ---- serial chunk scan: one chain per thread (n = tid&63, bp = wv) ----
    {
        int n = tid & 63, bp = tid >> 6;
        float2 wt = wTg[h * 64 + n];             // w^64
        float sr = 0.0f, si = 0.0f;
#pragma unroll 1
        for (int c = 0; c < 16; ++c) {
            int row = bp * 16 + c;
            char* p = sS + row * 512 + (((n >> 1) ^ (row & 7)) * 16)
                      + (n & 1) * 8;
            float2 loc = *(float2*)p;
            *(float2*)p = make_float2(sr, si);   // S_in before update
            float nr2 = wt.x * sr - wt.y * si + loc.x;
            float ni2 = wt.x * si + wt.y * sr + loc.y;
            sr = nr2; si = ni2;
        }
    }
    __syncthreads();

    // ---- GEMM2: y += S_in[64 x 128] * Qt^T, K=128 (4 k-steps) ----
#pragma unroll
    for (int ks = 0; ks < 4; ++ks) {
        int row = wv * 16 + lm;
        int cf0 = ks * 8 + q * 2;
        f32x4 a0 = *(const f32x4*)(sS + row * 512 + ((cf0 ^ (row & 7)) * 16));
        f32x4 a1 = *(const f32x4*)(sS + row * 512 + (((cf0 + 1) ^ (row & 7)) * 16));
        bf16x8 af;
        af[0] = (__bf16)a0[0]; af[1] = (__bf16)a0[1];
        af[2] = (__bf16)a0[2]; af[3] = (__bf16)a0[3];
        af[4] = (__bf16)a1[0]; af[5] = (__bf16)a1[1];
        af[6] = (__bf16)a1[2]; af[7] = (__bf16)a1[3];
#pragma unroll
        for (int nt = 0; nt < 4; ++nt) {
            int trow = nt * 16 + lm;
            int clog = ks * 4 + q;
            bf16x8 bq = *(const bf16x8*)(sQ + trow * 256 + ((clog ^ (trow & 3)) * 16));
            acc[nt] = __builtin_amdgcn_mfma_f32_16x16x32_bf16(
                af, bq, acc[nt], 0, 0, 0);
        }
    }

    // ---- epilogue: D-skip (bf16 x) + GELU -> yTa ----
    float Dh = Dv[h];
#pragma unroll
    for (int nt = 0; nt < 4; ++nt)
#pragma unroll
        for (int r = 0; r < 4; ++r) {
            int row = wv * 16 + q * 4 + r;
            int seq = (b0 + (row >> 4)) * H_ + h;
            int l   = (row & 15) * 64 + nt * 16 + lm;
            float xv = __bfloat162float(xTb[(size_t)seq * L_ + l]);
            float yv = acc[nt][r] + xv * Dh;
            yTa[(size_t)seq * L_ + l] = __float2bfloat16(gelu_tanh(yv));
        }
}

// ---------------------------------------------------------------------------
// K4: Z = Y @ Wt^T (+b), fused GLU epilogue.
// A-operand read DIRECTLY from yTa = Y^T [B*H, L] via ds_read_b64_tr_b16.
// NEW (this round): 64KB LDS DOUBLE-BUFFER with counted vmcnt across RAW
// s_barriers (T3-minimum). Per kt: issue stage(kt+1) into other buffer ->
// s_waitcnt vmcnt(8) (waits only PREVIOUS tile's 8 gll16, issued a full
// compute-phase earlier -> near-free) -> s_barrier -> compute(kt) ->
// s_barrier (so stage(kt+2) can't overwrite buffer still being read).
// Avoids the compiler's s_waitcnt vmcnt(0) drain that __syncthreads emits.
// ---------------------------------------------------------------------------
__global__ __launch_bounds__(256, 2) void gemm_glu(
        const __hip_bfloat16* __restrict__ Yt, const __hip_bfloat16* __restrict__ Wt,
        const float* __restrict__ bv, float* __restrict__ out) {
    __shared__ char lds[65536];
    // buffer p at lds + p*32768: sA@+0 (16K subtiled), sBa@+16384, sBg@+24576

    int tid = threadIdx.x, wv = tid >> 6, lane = tid & 63;
    int mb = (blockIdx.x & 127) * 128;
    int h0 = (blockIdx.x >> 7) * 64;
    int bat = mb >> 10;          // batch of this M-tile (128 | 1024)
    int l0 = mb & 1023;          // sequence-pos base
    int r8 = lane >> 3, c8 = lane & 7, csrc = c8 ^ r8;
    int wm = (wv >> 1) * 64, wn = (wv & 1) * 32;
    int lm = lane & 15, q = lane >> 4;

    // A-staging per-lane decode: issue kq -> k = kq*4 + kA, m-offset mA
    int kA = (lane >> 1) & 3;
    int mA = (lane >> 3) * 16 + (lane & 1) * 8;

    const char* Yb = (const char*)Yt;
    const char* Wb = (const char*)Wt;

    // stage tile t (t in [0,16)) into buffer buf
    auto stage = [&](char* buf, int t) {
        int k0b = t * 128;
#pragma unroll
        for (int j = 0; j < 4; ++j) {
            int kq = wv * 4 + j;
            gll16(Yb + ((size_t)(bat * H_ + t * 64 + kq * 4 + kA)) * 2048
                      + (size_t)(l0 + mA) * 2,
                  buf + kq * 1024);
        }
#pragma unroll
        for (int j = 0; j < 2; ++j) {
            int i = wv * 2 + j;
            int n = h0 + i * 8 + r8;
            gll16(Wb + (size_t)n * 2048 + k0b + csrc * 16,
                  buf + 16384 + i * 1024);
            gll16(Wb + (size_t)(n + 1024) * 2048 + k0b + csrc * 16,
                  buf + 24576 + i * 1024);
        }
    };

    f32x4 accA[4][2], accG[4][2];
#pragma unroll
    for (int i = 0; i < 4; ++i)
#pragma unroll
        for (int j = 0; j < 2; ++j) {
            accA[i][j] = (f32x4){0.f, 0.f, 0.f, 0.f};
            accG[i][j] = (f32x4){0.f, 0.f, 0.f, 0.f};
        }

    char* bufA = lds;
    char* bufB = lds + 32768;

    // prologue: stage tile 0
    stage(bufA, 0);

    auto body = [&](int kt, char* cur, char* nxt) {
        // issue NEXT tile's stage first (overlaps with the vmcnt wait + compute)
        if (kt < 15) {
            stage(nxt, kt + 1);
            asm volatile("s_waitcnt vmcnt(8)" ::: "memory");  // cur's 8 landed
        } else {
            asm volatile("s_waitcnt vmcnt(0)" ::: "memory");
        }
        __builtin_amdgcn_s_barrier();       // all waves' stage(kt) visible
        __builtin_amdgcn_sched_barrier(0);

        unsigned aBase = (unsigned)(size_t)cur;
        char* sBa = cur + 16384;
        char* sBg = cur + 24576;
#pragma unroll
        for (int kk = 0; kk < 2; ++kk) {
            int clog = kk * 4 + q;   // k-octet index for this lane-quad
            // ---- A-fragments: 2 tr reads per mt, lane slot = lm*8 ----
            unsigned long long r0[4], r1[4];
#pragma unroll
            for (int mt = 0; mt < 4; ++mt) {
                unsigned a0 = aBase + (unsigned)(clog * 2048
                               + ((wm >> 4) + mt) * 128 + lm * 8);
                r0[mt] = tr16(a0);
                r1[mt] = tr16(a0 + 1024);
            }
            // ---- B-fragments (compiler-managed ds_read_b128) ----
            bf16x8 ba[2], bg[2];
#pragma unroll
            for (int nt = 0; nt < 2; ++nt) {
                int n = wn + nt * 16 + lm;
                int cph = (clog ^ (n & 7)) * 16;
                ba[nt] = *(const bf16x8*)(sBa + n * 128 + cph);
                bg[nt] = *(const bf16x8*)(sBg + n * 128 + cph);
            }
            // tr results are untracked by the compiler: drain + fence (rule 18)
            asm volatile("s_waitcnt lgkmcnt(0)" ::: "memory");
            __builtin_amdgcn_sched_barrier(0);
#pragma unroll
            for (int mt = 0; mt < 4; ++mt) {
                union { unsigned long long u[2]; bf16x8 v; } cv;
                cv.u[0] = r0[mt]; cv.u[1] = r1[mt];
                bf16x8 af = cv.v;
#pragma unroll
                for (int nt = 0; nt < 2; ++nt) {
                    accA[mt][nt] = __builtin_amdgcn_mfma_f32_16x16x32_bf16(
                        af, ba[nt], accA[mt][nt], 0, 0, 0);
                    accG[mt][nt] = __builtin_amdgcn_mfma_f32_16x16x32_bf16(
                        af, bg[nt], accG[mt][nt], 0, 0, 0);
                }
            }
        }
        __builtin_amdgcn_sched_barrier(0);
        __builtin_amdgcn_s_barrier();       // all done reading cur before it
                                            // is restaged at kt+2
    };

#pragma unroll 1
    for (int kt2 = 0; kt2 < 16; kt2 += 2) {
        body(kt2, bufA, bufB);
        body(kt2 + 1, bufB, bufA);
    }

#pragma unroll
    for (int mt = 0; mt < 4; ++mt)
#pragma unroll
        for (int nt = 0; nt < 2; ++nt) {
            int hc = h0 + wn + nt * 16 + lm;
            float bba = bv[hc], bbg = bv[hc + 1024];
#pragma unroll
            for (int r = 0; r < 4; ++r) {
                int m = mb + wm + mt * 16 + q * 4 + r;
                float za = accA[mt][nt][r] + bba;
                float zg = accG[mt][nt][r] + bbg;
                out[(size_t)m * H_ + hc] = za / (1.0f + expf(-zg));
            }
        }
}

// ---------------------------------------------------------------------------
extern "C" void kernel_launch(void* const* d_in, const int* in_sizes, int n_in,
                              void* d_out, int out_size, void* d_ws, size_t ws_size,
                              hipStream_t stream) {
    const float* x      = (const float*)d_in[0];
    const float* log_dt = (const float*)d_in[1];
    const float* Arl    = (const float*)d_in[2];
    const float* Aim    = (const float*)d_in[3];
    const float* Cr     = (const float*)d_in[4];
    const float* Ci     = (const float*)d_in[5];
    const float* Dv     = (const float*)d_in[6];
    const float* W      = (const float*)d_in[7];
    const float* bv     = (const float*)d_in[8];
    float* out = (float*)d_out;

    char* ws = (char*)d_ws;
    // layout:
    //   [0,  32M) xTb bf16
    //   [32M,64M) yTa bf16 (consumed directly by gemm_glu as A^T)
    //   [64M,88M) Bt | [88M,104M) Qt | [104M,104.5M) wT | [105M,109M) Wt
    __hip_bfloat16*  xTb = (__hip_bfloat16*)ws;
    __hip_bfloat16*  yTa = (__hip_bfloat16*)(ws + (32u << 20));
    char*            Btg = ws + (64u << 20);
    char*            Qtg = Btg + (size_t)H_ * 192 * 64 * 2;          // +24M
    float2*          wTg = (float2*)(ws + (104u << 20));
    __hip_bfloat16*  Wt  = (__hip_bfloat16*)(ws + (105u << 20));

    prep<<<2176, 256, 0, stream>>>(x, log_dt, Arl, Aim, Cr, Ci, W,
                                   xTb, (__hip_bfloat16*)Btg,
                                   (__hip_bfloat16*)Qtg, wTg, Wt);
    chunk_scan<<<4096, 256, 0, stream>>>(xTb, Btg, Qtg, wTg, Dv, yTa);
    gemm_glu<<<2048, 256, 0, stream>>>(yTa, Wt, bv, out);
}